// Round 6
// baseline (621.807 us; speedup 1.0000x reference)
//
#include <hip/hip_runtime.h>

// GraphAttentionLayer on MI355X (gfx950)
// N=8192, IN_F=128, N_HID=64, OUT_F=128
//
// R15: R12 base (proven 440us) + global QK frags with FIXED load order
// + 3 blocks/CU occupancy.
//   R14 post-mortem: depth-2 staging regs (+96 VGPR live) regressed
//   (464us) -- reverted. R12's attn ~111us ~= serial sum of pipes: with
//   grid 512 and 78KB LDS, only 2 blocks/CU -> no cross-block overlap.
//   R15: (1) QK B-frags straight from global L1/L2 (per-chunk wht slice
//   = 256KB at C=8), frag loads at LOOP TOP, staging issued AFTER them:
//   vmcnt retires in-order, so waiting on the older frags no longer
//   drains the newer HBM adj stream (R11's 8000cyc/iter bug).
//   (2) Bst deleted -> LDS 43KB; C=8 -> grid 1024; launch_bounds(256,3)
//   -> 3 blocks/CU, 12 waves/CU latency hiding.
// Kept from R10/R12 byte-identical: swapped-QK in-register softmax,
// base-2 softmax (log2e folded into Whs), exact rescale-skip, packed
// b64 Pbuf writes, hi/lo split QK precision, rotated Wst (conflict-free
// PV reads), double-buffered Wst/Mbuf, ONE __syncthreads per iter.

#define NN 8192
#define INF_ 128
#define NHID 64
#define OUTF 128
#define NEGC -9.0e15f

typedef unsigned short u16;
typedef __attribute__((ext_vector_type(8))) short bf16x8;
typedef __attribute__((ext_vector_type(4))) float f32x4;
typedef __attribute__((ext_vector_type(4))) int i32x4;
typedef __attribute__((ext_vector_type(4))) unsigned u32x4;

static __device__ __forceinline__ u16 f2bf(float x) {
  union { float f; unsigned u; } v; v.f = x;
  unsigned lsb = (v.u >> 16) & 1u;
  v.u += 0x7fffu + lsb;            // round-to-nearest-even
  return (u16)(v.u >> 16);
}
static __device__ __forceinline__ float bf2f(u16 h) {
  union { float f; unsigned u; } v; v.u = ((unsigned)h) << 16;
  return v.f;
}
static __device__ __forceinline__ f32x4 mfma16(bf16x8 a, bf16x8 b, f32x4 c) {
  return __builtin_amdgcn_mfma_f32_16x16x32_bf16(a, b, c, 0, 0, 0);
}

// ---------------------------------------------------------------- kernel 1
__global__ __launch_bounds__(256) void proj_kernel(
    const float* __restrict__ h, const float* __restrict__ Ws,
    const float* __restrict__ Wt, const float* __restrict__ Wc,
    u16* __restrict__ whs_hi, u16* __restrict__ whs_lo,
    u16* __restrict__ wht_hi, u16* __restrict__ wht_lo,
    u16* __restrict__ whcT) {
  __shared__ f32x4 hbuf[8][32];   // 8 rows x 128 k
  const int tid = threadIdx.x;
  const int r0 = blockIdx.x * 8;
  hbuf[tid >> 5][tid & 31] =
      reinterpret_cast<const f32x4*>(h)[(size_t)r0 * 32 + tid];
  __syncthreads();

  float acc[8];
#pragma unroll
  for (int r = 0; r < 8; ++r) acc[r] = 0.f;

  if (tid < 128) {
    const float* W = (tid < 64) ? (Ws + tid) : (Wt + (tid - 64));
#pragma unroll 4
    for (int k4 = 0; k4 < 32; ++k4) {
      float w0 = W[(k4 * 4 + 0) * NHID];
      float w1 = W[(k4 * 4 + 1) * NHID];
      float w2 = W[(k4 * 4 + 2) * NHID];
      float w3 = W[(k4 * 4 + 3) * NHID];
#pragma unroll
      for (int r = 0; r < 8; ++r) {
        f32x4 hv = hbuf[r][k4];
        acc[r] += hv.x * w0 + hv.y * w1 + hv.z * w2 + hv.w * w3;
      }
    }
    const int col = tid & 63;
    // fold log2(e) into the Whs side so softmax runs in base 2
    const float sc = (tid < 64) ? 1.4426950408889634f : 1.0f;
    u16* hi = (tid < 64) ? whs_hi : wht_hi;
    u16* lo = (tid < 64) ? whs_lo : wht_lo;
#pragma unroll
    for (int r = 0; r < 8; ++r) {
      float v = acc[r] * sc;
      u16 hb = f2bf(v);
      hi[(size_t)(r0 + r) * NHID + col] = hb;
      lo[(size_t)(r0 + r) * NHID + col] = f2bf(v - bf2f(hb));
    }
  } else {
    const int col = tid - 128;
    const float* W = Wc + col;
#pragma unroll 4
    for (int k4 = 0; k4 < 32; ++k4) {
      float w0 = W[(k4 * 4 + 0) * OUTF];
      float w1 = W[(k4 * 4 + 1) * OUTF];
      float w2 = W[(k4 * 4 + 2) * OUTF];
      float w3 = W[(k4 * 4 + 3) * OUTF];
#pragma unroll
      for (int r = 0; r < 8; ++r) {
        f32x4 hv = hbuf[r][k4];
        acc[r] += hv.x * w0 + hv.y * w1 + hv.z * w2 + hv.w * w3;
      }
    }
    union { u16 s[8]; u32x4 v; } pk;
#pragma unroll
    for (int r = 0; r < 8; ++r) pk.s[r] = f2bf(acc[r]);
    *reinterpret_cast<u32x4*>(whcT + (size_t)col * NN + r0) = pk.v;
  }
}

// ---------------------------------------------------------------- kernel 2
// 4 waves x 16 rows = 64 rows/block, CT=64 cols/iter, 3 blocks/CU.
__global__ __launch_bounds__(256, 3) void attn_kernel(
    const u16* __restrict__ whs_hi, const u16* __restrict__ whs_lo,
    const u16* __restrict__ wht_hi, const u16* __restrict__ wht_lo,
    const u16* __restrict__ whcT, const int* __restrict__ adj,
    float* __restrict__ Opart, float* __restrict__ mpart,
    float* __restrict__ lpart, float* __restrict__ out,
    int iters, int cshift, int final_write) {
  __shared__ __align__(16) u16 Wst[2][128 * 64];     // 32768 B (whcT, rotated)
  __shared__ __align__(16) u16 Pbuf[4][16][72];      //  9216 B
  __shared__ __align__(16) u16 Mbuf[2][64][4];       //  1024 B

  const int tid = threadIdx.x;
  const int w = tid >> 6;       // wave 0..3
  const int lane = tid & 63;
  const int q = lane >> 4;
  const int ln = lane & 15;
  const int chunk = blockIdx.x & ((1 << cshift) - 1);
  const int rb = blockIdx.x >> cshift;
  const int rowB = rb * 64;
  const int row0 = rowB + w * 16;

  // staging roles (fully coalesced global reads)
  const int wocol = tid >> 1;                // whcT: ocol 0..127
  const int wjh = tid & 1;                   //       j-half
  const u16* wg = whcT + (size_t)wocol * NN + wjh * 32;
  // rotated 16B-subchunk positions: logical s = wjh*4 + i -> p = (s+ocol)&7
  int wsp[4];
#pragma unroll
  for (int i = 0; i < 4; ++i) wsp[i] = ((wjh * 4 + i + wocol) & 7) * 8;
  const int arow = tid >> 2;                 // adj: row 0..63
  const int agrp = tid & 3;                  //      16-col group
  const int* ag = adj + (size_t)(rowB + arow) * NN + agrp * 16;

  // loop-invariant Whs fragments (rows row0+ln, 64 k hi/lo) — MFMA B operand
  bf16x8 a_hi[2], a_lo[2];
#pragma unroll
  for (int kh = 0; kh < 2; ++kh) {
    a_hi[kh] = *reinterpret_cast<const bf16x8*>(
        whs_hi + (size_t)(row0 + ln) * NHID + kh * 32 + q * 8);
    a_lo[kh] = *reinterpret_cast<const bf16x8*>(
        whs_lo + (size_t)(row0 + ln) * NHID + kh * 32 + q * 8);
  }

  f32x4 oacc[8];
#pragma unroll
  for (int ot = 0; ot < 8; ++ot)
#pragma unroll
    for (int g = 0; g < 4; ++g) oacc[ot][g] = 0.f;

  // per-lane online-softmax state for row (row0 + ln); replicated across q
  float m_old = -__builtin_inff();
  float l_run = 0.f;

  const int jbase = chunk * iters;   // in 64-col tiles

  // ---- preload tile 0 into buffer 0 (Wst + Mbuf; wht needs no LDS)
  {
    const size_t j0 = (size_t)jbase * 64;
    const u32x4* pw = reinterpret_cast<const u32x4*>(wg + j0);
    u32x4 w0 = pw[0], w1 = pw[1], w2 = pw[2], w3 = pw[3];
    const i32x4* pa = reinterpret_cast<const i32x4*>(ag + j0);
    i32x4 a0 = __builtin_nontemporal_load(pa + 0);
    i32x4 a1 = __builtin_nontemporal_load(pa + 1);
    i32x4 a2 = __builtin_nontemporal_load(pa + 2);
    i32x4 a3 = __builtin_nontemporal_load(pa + 3);
    *reinterpret_cast<u32x4*>(&Wst[0][wocol * 64 + wsp[0]]) = w0;
    *reinterpret_cast<u32x4*>(&Wst[0][wocol * 64 + wsp[1]]) = w1;
    *reinterpret_cast<u32x4*>(&Wst[0][wocol * 64 + wsp[2]]) = w2;
    *reinterpret_cast<u32x4*>(&Wst[0][wocol * 64 + wsp[3]]) = w3;
    unsigned mw = 0;
    mw |= (a0.x>0?1u:0u)<<0  | (a0.y>0?1u:0u)<<1  | (a0.z>0?1u:0u)<<2  | (a0.w>0?1u:0u)<<3;
    mw |= (a1.x>0?1u:0u)<<4  | (a1.y>0?1u:0u)<<5  | (a1.z>0?1u:0u)<<6  | (a1.w>0?1u:0u)<<7;
    mw |= (a2.x>0?1u:0u)<<8  | (a2.y>0?1u:0u)<<9  | (a2.z>0?1u:0u)<<10 | (a2.w>0?1u:0u)<<11;
    mw |= (a3.x>0?1u:0u)<<12 | (a3.y>0?1u:0u)<<13 | (a3.z>0?1u:0u)<<14 | (a3.w>0?1u:0u)<<15;
    Mbuf[0][arow][agrp] = (u16)mw;
  }
  __syncthreads();

  for (int jt = 0; jt < iters; ++jt) {
    const int buf = jt & 1;

    // ---- 1. QK B-fragments from global (L1/L2-resident slice), FIRST so
    // they are the OLDEST vmem ops: waiting on them does not drain the
    // staging stream issued below (vmcnt retires in order).
    bf16x8 bh0[4], bh1[4], bl0[4], bl1[4];
    {
      const size_t jr0 = ((size_t)(jbase + jt) * 64 + ln) * NHID + q * 8;
#pragma unroll
      for (int nt = 0; nt < 4; ++nt) {
        const size_t jr = jr0 + (size_t)nt * 16 * NHID;
        bh0[nt] = *reinterpret_cast<const bf16x8*>(wht_hi + jr);
        bh1[nt] = *reinterpret_cast<const bf16x8*>(wht_hi + jr + 32);
        bl0[nt] = *reinterpret_cast<const bf16x8*>(wht_lo + jr);
        bl1[nt] = *reinterpret_cast<const bf16x8*>(wht_lo + jr + 32);
      }
    }

    // ---- 2. issue next tile's staging loads (land during this iter)
    u32x4 sw0, sw1, sw2, sw3;
    i32x4 ad0, ad1, ad2, ad3;
    if (jt + 1 < iters) {
      const size_t j1 = (size_t)(jbase + jt + 1) * 64;
      const u32x4* pw = reinterpret_cast<const u32x4*>(wg + j1);
      sw0 = pw[0]; sw1 = pw[1]; sw2 = pw[2]; sw3 = pw[3];
      const i32x4* pa = reinterpret_cast<const i32x4*>(ag + j1);
      ad0 = __builtin_nontemporal_load(pa + 0);
      ad1 = __builtin_nontemporal_load(pa + 1);
      ad2 = __builtin_nontemporal_load(pa + 2);
      ad3 = __builtin_nontemporal_load(pa + 3);
    }

    // ---- mask bits for this lane's row (row0+ln): one 8B read
    const unsigned* mrow =
        reinterpret_cast<const unsigned*>(&Mbuf[buf][w * 16 + ln][0]);
    const unsigned m0 = mrow[0];   // cols j 0..31
    const unsigned m1 = mrow[1];   // cols j 32..63

    // ---- scores, TRANSPOSED: lane (q,ln) holds S[row0+ln][nt*16+q*4+g]
    float s[4][4];
#pragma unroll
    for (int nt = 0; nt < 4; ++nt) {
      f32x4 sa;
#pragma unroll
      for (int g = 0; g < 4; ++g) sa[g] = 0.f;
      sa = mfma16(bh0[nt], a_lo[0], sa);
      sa = mfma16(bl0[nt], a_hi[0], sa);
      sa = mfma16(bh0[nt], a_hi[0], sa);
      sa = mfma16(bh1[nt], a_lo[1], sa);
      sa = mfma16(bl1[nt], a_hi[1], sa);
      sa = mfma16(bh1[nt], a_hi[1], sa);
      const unsigned mm = (nt & 2) ? m1 : m0;
#pragma unroll
      for (int g = 0; g < 4; ++g) {
        unsigned bit = (mm >> ((nt & 1) * 16 + q * 4 + g)) & 1u;
        s[nt][g] = bit ? sa[g] : NEGC;
      }
    }

    // ---- row max: in-lane tree + 2-shfl butterfly over the q replicas
    float rmax;
    {
      float t0 = fmaxf(fmaxf(s[0][0], s[0][1]), fmaxf(s[0][2], s[0][3]));
      float t1 = fmaxf(fmaxf(s[1][0], s[1][1]), fmaxf(s[1][2], s[1][3]));
      float t2 = fmaxf(fmaxf(s[2][0], s[2][1]), fmaxf(s[2][2], s[2][3]));
      float t3 = fmaxf(fmaxf(s[3][0], s[3][1]), fmaxf(s[3][2], s[3][3]));
      rmax = fmaxf(fmaxf(t0, t1), fmaxf(t2, t3));
    }
    rmax = fmaxf(rmax, __shfl_xor(rmax, 16));
    rmax = fmaxf(rmax, __shfl_xor(rmax, 32));

    // ---- exact rescale-skip: when no row grew, alpha == 1 exactly
    if (__any(rmax > m_old)) {
      const float mn = fmaxf(m_old, rmax);
      const float al = __builtin_amdgcn_exp2f(m_old - mn);
      m_old = mn;
      l_run *= al;
      float alg[4];
#pragma unroll
      for (int g = 0; g < 4; ++g) alg[g] = __shfl(al, q * 4 + g);
#pragma unroll
      for (int ot = 0; ot < 8; ++ot)
#pragma unroll
        for (int g = 0; g < 4; ++g) oacc[ot][g] *= alg[g];
    }

    // ---- P = exp2(s - m), packed b64 writes to Pbuf, row-sum
    float ps = 0.f;
#pragma unroll
    for (int nt = 0; nt < 4; ++nt) {
      float p0 = __builtin_amdgcn_exp2f(s[nt][0] - m_old);
      float p1 = __builtin_amdgcn_exp2f(s[nt][1] - m_old);
      float p2 = __builtin_amdgcn_exp2f(s[nt][2] - m_old);
      float p3 = __builtin_amdgcn_exp2f(s[nt][3] - m_old);
      ps += (p0 + p1) + (p2 + p3);
      union { u16 h[4]; unsigned long long u; } pk;
      pk.h[0] = f2bf(p0); pk.h[1] = f2bf(p1);
      pk.h[2] = f2bf(p2); pk.h[3] = f2bf(p3);
      *reinterpret_cast<unsigned long long*>(
          &Pbuf[w][ln][nt * 16 + q * 4]) = pk.u;
    }
    ps += __shfl_xor(ps, 16);
    ps += __shfl_xor(ps, 32);
    l_run += ps;

    // ---- PV from LDS (Pbuf A-frags; rotated Wst B-frags)
#pragma unroll
    for (int kh = 0; kh < 2; ++kh) {
      bf16x8 pa = *reinterpret_cast<const bf16x8*>(
          &Pbuf[w][ln][kh * 32 + q * 8]);
#pragma unroll
      for (int ot = 0; ot < 8; ++ot) {
        const int ocol = ot * 16 + ln;
        const int pp = ((kh << 2) + q + ocol) & 7;   // (s + ocol) & 7
        bf16x8 wb = *reinterpret_cast<const bf16x8*>(
            &Wst[buf][ocol * 64 + pp * 8]);
        oacc[ot] = mfma16(pa, wb, oacc[ot]);
      }
    }

    // ---- commit next tile into buf^1 (double-buffered), ONE barrier
    if (jt + 1 < iters) {
      const int nb = buf ^ 1;
      *reinterpret_cast<u32x4*>(&Wst[nb][wocol * 64 + wsp[0]]) = sw0;
      *reinterpret_cast<u32x4*>(&Wst[nb][wocol * 64 + wsp[1]]) = sw1;
      *reinterpret_cast<u32x4*>(&Wst[nb][wocol * 64 + wsp[2]]) = sw2;
      *reinterpret_cast<u32x4*>(&Wst[nb][wocol * 64 + wsp[3]]) = sw3;
      unsigned mw = 0;
      mw |= (ad0.x>0?1u:0u)<<0  | (ad0.y>0?1u:0u)<<1  | (ad0.z>0?1u:0u)<<2  | (ad0.w>0?1u:0u)<<3;
      mw |= (ad1.x>0?1u:0u)<<4  | (ad1.y>0?1u:0u)<<5  | (ad1.z>0?1u:0u)<<6  | (ad1.w>0?1u:0u)<<7;
      mw |= (ad2.x>0?1u:0u)<<8  | (ad2.y>0?1u:0u)<<9  | (ad2.z>0?1u:0u)<<10 | (ad2.w>0?1u:0u)<<11;
      mw |= (ad3.x>0?1u:0u)<<12 | (ad3.y>0?1u:0u)<<13 | (ad3.z>0?1u:0u)<<14 | (ad3.w>0?1u:0u)<<15;
      Mbuf[nb][arow][agrp] = (u16)mw;
    }
    __syncthreads();
  }

  // ---- epilogue
  if (final_write) {
    float lr[4];
#pragma unroll
    for (int g = 0; g < 4; ++g) lr[g] = __shfl(l_run, q * 4 + g);
#pragma unroll
    for (int ot = 0; ot < 8; ++ot)
#pragma unroll
      for (int g = 0; g < 4; ++g) {
        const int r = row0 + q * 4 + g;
        out[(size_t)r * OUTF + ot * 16 + ln] = oacc[ot][g] / lr[g];
      }
  } else {
#pragma unroll
    for (int ot = 0; ot < 8; ++ot)
#pragma unroll
      for (int g = 0; g < 4; ++g) {
        const int r = row0 + q * 4 + g;
        Opart[((size_t)chunk * NN + r) * OUTF + ot * 16 + ln] = oacc[ot][g];
      }
    if (lane < 16) {   // q==0 lanes each own one row's stats
      mpart[chunk * NN + row0 + ln] = m_old;
      lpart[chunk * NN + row0 + ln] = l_run;
    }
  }
}

// ---------------------------------------------------------------- kernel 3
__global__ __launch_bounds__(256) void combine_kernel(
    const float* __restrict__ Opart, const float* __restrict__ mpart,
    const float* __restrict__ lpart, float* __restrict__ out, int C) {
  const int idx = blockIdx.x * 256 + threadIdx.x;  // over N*OUTF
  const int row = idx >> 7;
  float M = -__builtin_inff();
  for (int c = 0; c < C; ++c) M = fmaxf(M, mpart[c * NN + row]);
  float den = 0.f, num = 0.f;
  for (int c = 0; c < C; ++c) {
    float wgt = __builtin_amdgcn_exp2f(mpart[c * NN + row] - M);
    den += lpart[c * NN + row] * wgt;
    num += Opart[(size_t)c * NN * OUTF + idx] * wgt;
  }
  out[idx] = num / den;
}

// ---------------------------------------------------------------- launch
extern "C" void kernel_launch(void* const* d_in, const int* in_sizes, int n_in,
                              void* d_out, int out_size, void* d_ws, size_t ws_size,
                              hipStream_t stream) {
  const float* h   = (const float*)d_in[0];
  const int*   adj = (const int*)d_in[1];
  const float* Ws  = (const float*)d_in[2];
  const float* Wt  = (const float*)d_in[3];
  const float* Wc  = (const float*)d_in[4];
  float* out = (float*)d_out;

  char* ws = (char*)d_ws;
  const size_t MB = 1024 * 1024;
  // ws: whs_hi|whs_lo|wht_hi|wht_lo (1MB each) | whcT (2MB)
  //     | mpart (256KB) | lpart (256KB) | Opart (C*4MB)
  u16* whs_hi = (u16*)(ws);
  u16* whs_lo = (u16*)(ws + 1 * MB);
  u16* wht_hi = (u16*)(ws + 2 * MB);
  u16* wht_lo = (u16*)(ws + 3 * MB);
  u16* whcT   = (u16*)(ws + 4 * MB);
  float* mpart = (float*)(ws + 6 * MB);
  float* lpart = (float*)(ws + 6 * MB + 256 * 1024);
  float* Opart = (float*)(ws + 6 * MB + 512 * 1024);

  // C=8 -> grid 1024, 43KB LDS -> 3 blocks/CU; C=1 fallback writes out.
  int C = 8, cshift = 3;
  if (6 * MB + 512 * 1024 + (size_t)C * NN * OUTF * sizeof(float) > ws_size) {
    C = 1; cshift = 0;
  }
  const int final_write = (C == 1) ? 1 : 0;
  const int iters = NN / (C * 64);     // 64-col tiles per chunk

  proj_kernel<<<NN / 8, 256, 0, stream>>>(h, Ws, Wt, Wc, whs_hi, whs_lo,
                                          wht_hi, wht_lo, whcT);
  attn_kernel<<<(NN / 64) * C, 256, 0, stream>>>(
      whs_hi, whs_lo, wht_hi, wht_lo, whcT, adj, Opart, mpart, lpart, out,
      iters, cshift, final_write);
  if (!final_write)
    combine_kernel<<<NN * OUTF / 256, 256, 0, stream>>>(Opart, mpart, lpart,
                                                        out, C);
}

// Round 7
// 438.095 us; speedup vs baseline: 1.4193x; 1.4193x over previous
//
#include <hip/hip_runtime.h>

// GraphAttentionLayer on MI355X (gfx950)
// N=8192, IN_F=128, N_HID=64, OUT_F=128
//
// R16: exact R12 base (proven 440us) + two zero-risk micro-levers.
//   R15 post-mortem: register-direct QK frags confirmed dead (303us attn
//   even with fixed load order) -- per-wave-redundant L2 traffic's latency
//   can't be hidden in a barriered loop; LDS staging IS the broadcast
//   that amortizes it. R14 showed commit vmcnt drain is already covered
//   by the compute phase. In-register P->PV handoff audited: needs 16
//   ds_permutes vs Pbuf's 6 LDS ops -- Pbuf is the cheapest permute.
//   R16 levers:
//   (1) v_cvt_pk_bf16_f32 for the P->bf16 pack: replaces 16 manual
//       f2bf bit-twiddles (~48 VALU instr/lane-iter) with 8 hw packs.
//       Same RNE rounding -> bit-identical output.
//   (2) s_setprio(1) around the QK and PV MFMA clusters (m191: +4-7%
//       attn): 2 co-resident blocks drift in phase; setprio lets the
//       MFMA-phase block preempt the other's staging/VALU phase.
// Kept byte-identical from R12: swapped-QK in-register softmax, base-2
// softmax (log2e folded into Whs), exact rescale-skip, hi/lo split QK
// precision, rotated Wst (bank-conflict-free PV), ALL LDS double-
// buffered, ONE __syncthreads per iter, 2 blocks/CU.

#define NN 8192
#define INF_ 128
#define NHID 64
#define OUTF 128
#define NEGC -9.0e15f

typedef unsigned short u16;
typedef __attribute__((ext_vector_type(8))) short bf16x8;
typedef __attribute__((ext_vector_type(4))) float f32x4;
typedef __attribute__((ext_vector_type(4))) int i32x4;
typedef __attribute__((ext_vector_type(4))) unsigned u32x4;

static __device__ __forceinline__ u16 f2bf(float x) {
  union { float f; unsigned u; } v; v.f = x;
  unsigned lsb = (v.u >> 16) & 1u;
  v.u += 0x7fffu + lsb;            // round-to-nearest-even
  return (u16)(v.u >> 16);
}
static __device__ __forceinline__ float bf2f(u16 h) {
  union { float f; unsigned u; } v; v.u = ((unsigned)h) << 16;
  return v.f;
}
static __device__ __forceinline__ unsigned pk2bf(float lo, float hi) {
  unsigned r;
  asm("v_cvt_pk_bf16_f32 %0, %1, %2" : "=v"(r) : "v"(lo), "v"(hi));
  return r;
}
static __device__ __forceinline__ f32x4 mfma16(bf16x8 a, bf16x8 b, f32x4 c) {
  return __builtin_amdgcn_mfma_f32_16x16x32_bf16(a, b, c, 0, 0, 0);
}

// ---------------------------------------------------------------- kernel 1
__global__ __launch_bounds__(256) void proj_kernel(
    const float* __restrict__ h, const float* __restrict__ Ws,
    const float* __restrict__ Wt, const float* __restrict__ Wc,
    u16* __restrict__ whs_hi, u16* __restrict__ whs_lo,
    u16* __restrict__ wht_hi, u16* __restrict__ wht_lo,
    u16* __restrict__ whcT) {
  __shared__ f32x4 hbuf[8][32];   // 8 rows x 128 k
  const int tid = threadIdx.x;
  const int r0 = blockIdx.x * 8;
  hbuf[tid >> 5][tid & 31] =
      reinterpret_cast<const f32x4*>(h)[(size_t)r0 * 32 + tid];
  __syncthreads();

  float acc[8];
#pragma unroll
  for (int r = 0; r < 8; ++r) acc[r] = 0.f;

  if (tid < 128) {
    const float* W = (tid < 64) ? (Ws + tid) : (Wt + (tid - 64));
#pragma unroll 4
    for (int k4 = 0; k4 < 32; ++k4) {
      float w0 = W[(k4 * 4 + 0) * NHID];
      float w1 = W[(k4 * 4 + 1) * NHID];
      float w2 = W[(k4 * 4 + 2) * NHID];
      float w3 = W[(k4 * 4 + 3) * NHID];
#pragma unroll
      for (int r = 0; r < 8; ++r) {
        f32x4 hv = hbuf[r][k4];
        acc[r] += hv.x * w0 + hv.y * w1 + hv.z * w2 + hv.w * w3;
      }
    }
    const int col = tid & 63;
    // fold log2(e) into the Whs side so softmax runs in base 2
    const float sc = (tid < 64) ? 1.4426950408889634f : 1.0f;
    u16* hi = (tid < 64) ? whs_hi : wht_hi;
    u16* lo = (tid < 64) ? whs_lo : wht_lo;
#pragma unroll
    for (int r = 0; r < 8; ++r) {
      float v = acc[r] * sc;
      u16 hb = f2bf(v);
      hi[(size_t)(r0 + r) * NHID + col] = hb;
      lo[(size_t)(r0 + r) * NHID + col] = f2bf(v - bf2f(hb));
    }
  } else {
    const int col = tid - 128;
    const float* W = Wc + col;
#pragma unroll 4
    for (int k4 = 0; k4 < 32; ++k4) {
      float w0 = W[(k4 * 4 + 0) * OUTF];
      float w1 = W[(k4 * 4 + 1) * OUTF];
      float w2 = W[(k4 * 4 + 2) * OUTF];
      float w3 = W[(k4 * 4 + 3) * OUTF];
#pragma unroll
      for (int r = 0; r < 8; ++r) {
        f32x4 hv = hbuf[r][k4];
        acc[r] += hv.x * w0 + hv.y * w1 + hv.z * w2 + hv.w * w3;
      }
    }
    union { u16 s[8]; u32x4 v; } pk;
#pragma unroll
    for (int r = 0; r < 8; ++r) pk.s[r] = f2bf(acc[r]);
    *reinterpret_cast<u32x4*>(whcT + (size_t)col * NN + r0) = pk.v;
  }
}

// ---------------------------------------------------------------- kernel 2
// 4 waves x 16 rows = 64 rows/block, CT=64 cols/iter, 2 blocks/CU.
__global__ __launch_bounds__(256, 2) void attn_kernel(
    const u16* __restrict__ whs_hi, const u16* __restrict__ whs_lo,
    const u16* __restrict__ wht_hi, const u16* __restrict__ wht_lo,
    const u16* __restrict__ whcT, const int* __restrict__ adj,
    float* __restrict__ Opart, float* __restrict__ mpart,
    float* __restrict__ lpart, float* __restrict__ out,
    int iters, int cshift, int final_write) {
  __shared__ __align__(16) u16 Bst[2][2][64 * 72];   // 36864 B (wht hi/lo)
  __shared__ __align__(16) u16 Wst[2][128 * 64];     // 32768 B (whcT, rotated)
  __shared__ __align__(16) u16 Pbuf[4][16][72];      //  9216 B
  __shared__ __align__(16) u16 Mbuf[2][64][4];       //  1024 B

  const int tid = threadIdx.x;
  const int w = tid >> 6;       // wave 0..3
  const int lane = tid & 63;
  const int q = lane >> 4;
  const int ln = lane & 15;
  const int chunk = blockIdx.x & ((1 << cshift) - 1);
  const int rb = blockIdx.x >> cshift;
  const int rowB = rb * 64;
  const int row0 = rowB + w * 16;

  // staging roles (fully coalesced global reads, 64 B/thread each stream)
  const int bcol = tid >> 2;                 // wht: col 0..63
  const int bsh = (tid >> 1) & 1;            //      hi/lo
  const int bkh = tid & 1;                   //      k-half
  const u16* bg = (bsh ? wht_lo : wht_hi) + (size_t)bcol * NHID + bkh * 32;
  const int wocol = tid >> 1;                // whcT: ocol 0..127
  const int wjh = tid & 1;                   //       j-half
  const u16* wg = whcT + (size_t)wocol * NN + wjh * 32;
  // rotated 16B-subchunk positions: logical s = wjh*4 + i -> p = (s+ocol)&7
  int wsp[4];
#pragma unroll
  for (int i = 0; i < 4; ++i) wsp[i] = ((wjh * 4 + i + wocol) & 7) * 8;
  const int arow = tid >> 2;                 // adj: row 0..63
  const int agrp = tid & 3;                  //      16-col group
  const int* ag = adj + (size_t)(rowB + arow) * NN + agrp * 16;

  // loop-invariant Whs fragments (rows row0+ln, 64 k hi/lo) — MFMA B operand
  bf16x8 a_hi[2], a_lo[2];
#pragma unroll
  for (int kh = 0; kh < 2; ++kh) {
    a_hi[kh] = *reinterpret_cast<const bf16x8*>(
        whs_hi + (size_t)(row0 + ln) * NHID + kh * 32 + q * 8);
    a_lo[kh] = *reinterpret_cast<const bf16x8*>(
        whs_lo + (size_t)(row0 + ln) * NHID + kh * 32 + q * 8);
  }

  f32x4 oacc[8];
#pragma unroll
  for (int ot = 0; ot < 8; ++ot)
#pragma unroll
    for (int g = 0; g < 4; ++g) oacc[ot][g] = 0.f;

  // per-lane online-softmax state for row (row0 + ln); replicated across q
  float m_old = -__builtin_inff();
  float l_run = 0.f;

  const int jbase = chunk * iters;   // in 64-col tiles

  // ---- preload tile 0 into buffer 0
  {
    const size_t j0 = (size_t)jbase * 64;
    const u32x4* p = reinterpret_cast<const u32x4*>(bg + j0 * NHID);
    u32x4 b0 = p[0], b1 = p[1], b2 = p[2], b3 = p[3];
    const u32x4* pw = reinterpret_cast<const u32x4*>(wg + j0);
    u32x4 w0 = pw[0], w1 = pw[1], w2 = pw[2], w3 = pw[3];
    const i32x4* pa = reinterpret_cast<const i32x4*>(ag + j0);
    i32x4 a0 = __builtin_nontemporal_load(pa + 0);
    i32x4 a1 = __builtin_nontemporal_load(pa + 1);
    i32x4 a2 = __builtin_nontemporal_load(pa + 2);
    i32x4 a3 = __builtin_nontemporal_load(pa + 3);
    u32x4* d = reinterpret_cast<u32x4*>(&Bst[0][bsh][bcol * 72 + bkh * 32]);
    d[0] = b0; d[1] = b1; d[2] = b2; d[3] = b3;
    *reinterpret_cast<u32x4*>(&Wst[0][wocol * 64 + wsp[0]]) = w0;
    *reinterpret_cast<u32x4*>(&Wst[0][wocol * 64 + wsp[1]]) = w1;
    *reinterpret_cast<u32x4*>(&Wst[0][wocol * 64 + wsp[2]]) = w2;
    *reinterpret_cast<u32x4*>(&Wst[0][wocol * 64 + wsp[3]]) = w3;
    unsigned mw = 0;
    mw |= (a0.x>0?1u:0u)<<0  | (a0.y>0?1u:0u)<<1  | (a0.z>0?1u:0u)<<2  | (a0.w>0?1u:0u)<<3;
    mw |= (a1.x>0?1u:0u)<<4  | (a1.y>0?1u:0u)<<5  | (a1.z>0?1u:0u)<<6  | (a1.w>0?1u:0u)<<7;
    mw |= (a2.x>0?1u:0u)<<8  | (a2.y>0?1u:0u)<<9  | (a2.z>0?1u:0u)<<10 | (a2.w>0?1u:0u)<<11;
    mw |= (a3.x>0?1u:0u)<<12 | (a3.y>0?1u:0u)<<13 | (a3.z>0?1u:0u)<<14 | (a3.w>0?1u:0u)<<15;
    Mbuf[0][arow][agrp] = (u16)mw;
  }
  __syncthreads();

  for (int jt = 0; jt < iters; ++jt) {
    const int buf = jt & 1;

    // ---- issue next tile's staging loads (land during this iter's compute)
    u32x4 sb0, sb1, sb2, sb3, sw0, sw1, sw2, sw3;
    i32x4 ad0, ad1, ad2, ad3;
    if (jt + 1 < iters) {
      const size_t j1 = (size_t)(jbase + jt + 1) * 64;
      const u32x4* p = reinterpret_cast<const u32x4*>(bg + j1 * NHID);
      sb0 = p[0]; sb1 = p[1]; sb2 = p[2]; sb3 = p[3];
      const u32x4* pw = reinterpret_cast<const u32x4*>(wg + j1);
      sw0 = pw[0]; sw1 = pw[1]; sw2 = pw[2]; sw3 = pw[3];
      const i32x4* pa = reinterpret_cast<const i32x4*>(ag + j1);
      ad0 = __builtin_nontemporal_load(pa + 0);
      ad1 = __builtin_nontemporal_load(pa + 1);
      ad2 = __builtin_nontemporal_load(pa + 2);
      ad3 = __builtin_nontemporal_load(pa + 3);
    }

    // ---- mask bits for this lane's row (row0+ln): one 8B read
    const unsigned* mrow =
        reinterpret_cast<const unsigned*>(&Mbuf[buf][w * 16 + ln][0]);
    const unsigned m0 = mrow[0];   // cols j 0..31
    const unsigned m1 = mrow[1];   // cols j 32..63

    // ---- scores, TRANSPOSED: lane (q,ln) holds S[row0+ln][nt*16+q*4+g]
    const u16* Bh = &Bst[buf][0][0];
    const u16* Bl = &Bst[buf][1][0];
    float s[4][4];
    __builtin_amdgcn_s_setprio(1);
#pragma unroll
    for (int nt = 0; nt < 4; ++nt) {
      const int base = (nt * 16 + ln) * 72 + q * 8;
      bf16x8 bh0 = *reinterpret_cast<const bf16x8*>(&Bh[base]);
      bf16x8 bh1 = *reinterpret_cast<const bf16x8*>(&Bh[base + 32]);
      bf16x8 bl0 = *reinterpret_cast<const bf16x8*>(&Bl[base]);
      bf16x8 bl1 = *reinterpret_cast<const bf16x8*>(&Bl[base + 32]);
      f32x4 sa;
#pragma unroll
      for (int g = 0; g < 4; ++g) sa[g] = 0.f;
      sa = mfma16(bh0, a_lo[0], sa);
      sa = mfma16(bl0, a_hi[0], sa);
      sa = mfma16(bh0, a_hi[0], sa);
      sa = mfma16(bh1, a_lo[1], sa);
      sa = mfma16(bl1, a_hi[1], sa);
      sa = mfma16(bh1, a_hi[1], sa);
      const unsigned mm = (nt & 2) ? m1 : m0;
#pragma unroll
      for (int g = 0; g < 4; ++g) {
        unsigned bit = (mm >> ((nt & 1) * 16 + q * 4 + g)) & 1u;
        s[nt][g] = bit ? sa[g] : NEGC;
      }
    }
    __builtin_amdgcn_s_setprio(0);

    // ---- row max: in-lane tree + 2-shfl butterfly over the q replicas
    float rmax;
    {
      float t0 = fmaxf(fmaxf(s[0][0], s[0][1]), fmaxf(s[0][2], s[0][3]));
      float t1 = fmaxf(fmaxf(s[1][0], s[1][1]), fmaxf(s[1][2], s[1][3]));
      float t2 = fmaxf(fmaxf(s[2][0], s[2][1]), fmaxf(s[2][2], s[2][3]));
      float t3 = fmaxf(fmaxf(s[3][0], s[3][1]), fmaxf(s[3][2], s[3][3]));
      rmax = fmaxf(fmaxf(t0, t1), fmaxf(t2, t3));
    }
    rmax = fmaxf(rmax, __shfl_xor(rmax, 16));
    rmax = fmaxf(rmax, __shfl_xor(rmax, 32));

    // ---- exact rescale-skip: when no row grew, alpha == 1 exactly
    if (__any(rmax > m_old)) {
      const float mn = fmaxf(m_old, rmax);
      const float al = __builtin_amdgcn_exp2f(m_old - mn);
      m_old = mn;
      l_run *= al;
      float alg[4];
#pragma unroll
      for (int g = 0; g < 4; ++g) alg[g] = __shfl(al, q * 4 + g);
#pragma unroll
      for (int ot = 0; ot < 8; ++ot)
#pragma unroll
        for (int g = 0; g < 4; ++g) oacc[ot][g] *= alg[g];
    }

    // ---- P = exp2(s - m), hw-packed bf16 (RNE, bit-identical to f2bf),
    //      b64 writes to Pbuf, row-sum
    float ps = 0.f;
#pragma unroll
    for (int nt = 0; nt < 4; ++nt) {
      float p0 = __builtin_amdgcn_exp2f(s[nt][0] - m_old);
      float p1 = __builtin_amdgcn_exp2f(s[nt][1] - m_old);
      float p2 = __builtin_amdgcn_exp2f(s[nt][2] - m_old);
      float p3 = __builtin_amdgcn_exp2f(s[nt][3] - m_old);
      ps += (p0 + p1) + (p2 + p3);
      union { unsigned d[2]; unsigned long long u; } pk;
      pk.d[0] = pk2bf(p0, p1);
      pk.d[1] = pk2bf(p2, p3);
      *reinterpret_cast<unsigned long long*>(
          &Pbuf[w][ln][nt * 16 + q * 4]) = pk.u;
    }
    ps += __shfl_xor(ps, 16);
    ps += __shfl_xor(ps, 32);
    l_run += ps;

    // ---- PV from LDS (Pbuf A-frags; rotated Wst B-frags)
    __builtin_amdgcn_s_setprio(1);
#pragma unroll
    for (int kh = 0; kh < 2; ++kh) {
      bf16x8 pa = *reinterpret_cast<const bf16x8*>(
          &Pbuf[w][ln][kh * 32 + q * 8]);
      const int pp = ((kh << 2) + q + ln) & 7;   // (s + ocol) & 7, ocol&7==ln&7
#pragma unroll
      for (int ot = 0; ot < 8; ++ot) {
        const int ocol = ot * 16 + ln;
        bf16x8 wb = *reinterpret_cast<const bf16x8*>(
            &Wst[buf][ocol * 64 + pp * 8]);
        oacc[ot] = mfma16(pa, wb, oacc[ot]);
      }
    }
    __builtin_amdgcn_s_setprio(0);

    // ---- commit next tile into buf^1 (all double-buffered), ONE barrier
    if (jt + 1 < iters) {
      const int nb = buf ^ 1;
      u32x4* d = reinterpret_cast<u32x4*>(&Bst[nb][bsh][bcol * 72 + bkh * 32]);
      d[0] = sb0; d[1] = sb1; d[2] = sb2; d[3] = sb3;
      *reinterpret_cast<u32x4*>(&Wst[nb][wocol * 64 + wsp[0]]) = sw0;
      *reinterpret_cast<u32x4*>(&Wst[nb][wocol * 64 + wsp[1]]) = sw1;
      *reinterpret_cast<u32x4*>(&Wst[nb][wocol * 64 + wsp[2]]) = sw2;
      *reinterpret_cast<u32x4*>(&Wst[nb][wocol * 64 + wsp[3]]) = sw3;
      unsigned mw = 0;
      mw |= (ad0.x>0?1u:0u)<<0  | (ad0.y>0?1u:0u)<<1  | (ad0.z>0?1u:0u)<<2  | (ad0.w>0?1u:0u)<<3;
      mw |= (ad1.x>0?1u:0u)<<4  | (ad1.y>0?1u:0u)<<5  | (ad1.z>0?1u:0u)<<6  | (ad1.w>0?1u:0u)<<7;
      mw |= (ad2.x>0?1u:0u)<<8  | (ad2.y>0?1u:0u)<<9  | (ad2.z>0?1u:0u)<<10 | (ad2.w>0?1u:0u)<<11;
      mw |= (ad3.x>0?1u:0u)<<12 | (ad3.y>0?1u:0u)<<13 | (ad3.z>0?1u:0u)<<14 | (ad3.w>0?1u:0u)<<15;
      Mbuf[buf ^ 1][arow][agrp] = (u16)mw;
    }
    __syncthreads();
  }

  // ---- epilogue
  if (final_write) {
    float lr[4];
#pragma unroll
    for (int g = 0; g < 4; ++g) lr[g] = __shfl(l_run, q * 4 + g);
#pragma unroll
    for (int ot = 0; ot < 8; ++ot)
#pragma unroll
      for (int g = 0; g < 4; ++g) {
        const int r = row0 + q * 4 + g;
        out[(size_t)r * OUTF + ot * 16 + ln] = oacc[ot][g] / lr[g];
      }
  } else {
#pragma unroll
    for (int ot = 0; ot < 8; ++ot)
#pragma unroll
      for (int g = 0; g < 4; ++g) {
        const int r = row0 + q * 4 + g;
        Opart[((size_t)chunk * NN + r) * OUTF + ot * 16 + ln] = oacc[ot][g];
      }
    if (lane < 16) {   // q==0 lanes each own one row's stats
      mpart[chunk * NN + row0 + ln] = m_old;
      lpart[chunk * NN + row0 + ln] = l_run;
    }
  }
}

// ---------------------------------------------------------------- kernel 3
__global__ __launch_bounds__(256) void combine_kernel(
    const float* __restrict__ Opart, const float* __restrict__ mpart,
    const float* __restrict__ lpart, float* __restrict__ out, int C) {
  const int idx = blockIdx.x * 256 + threadIdx.x;  // over N*OUTF
  const int row = idx >> 7;
  float M = -__builtin_inff();
  for (int c = 0; c < C; ++c) M = fmaxf(M, mpart[c * NN + row]);
  float den = 0.f, num = 0.f;
  for (int c = 0; c < C; ++c) {
    float wgt = __builtin_amdgcn_exp2f(mpart[c * NN + row] - M);
    den += lpart[c * NN + row] * wgt;
    num += Opart[(size_t)c * NN * OUTF + idx] * wgt;
  }
  out[idx] = num / den;
}

// ---------------------------------------------------------------- launch
extern "C" void kernel_launch(void* const* d_in, const int* in_sizes, int n_in,
                              void* d_out, int out_size, void* d_ws, size_t ws_size,
                              hipStream_t stream) {
  const float* h   = (const float*)d_in[0];
  const int*   adj = (const int*)d_in[1];
  const float* Ws  = (const float*)d_in[2];
  const float* Wt  = (const float*)d_in[3];
  const float* Wc  = (const float*)d_in[4];
  float* out = (float*)d_out;

  char* ws = (char*)d_ws;
  const size_t MB = 1024 * 1024;
  // ws: whs_hi|whs_lo|wht_hi|wht_lo (1MB each) | whcT (2MB)
  //     | mpart (256KB) | lpart (256KB) | Opart (C*4MB)
  u16* whs_hi = (u16*)(ws);
  u16* whs_lo = (u16*)(ws + 1 * MB);
  u16* wht_hi = (u16*)(ws + 2 * MB);
  u16* wht_lo = (u16*)(ws + 3 * MB);
  u16* whcT   = (u16*)(ws + 4 * MB);
  float* mpart = (float*)(ws + 6 * MB);
  float* lpart = (float*)(ws + 6 * MB + 256 * 1024);
  float* Opart = (float*)(ws + 6 * MB + 512 * 1024);

  // C=4 -> grid 512 = 2 blocks/CU; C=1 fallback writes out directly.
  int C = 4, cshift = 2;
  if (6 * MB + 512 * 1024 + (size_t)C * NN * OUTF * sizeof(float) > ws_size) {
    C = 1; cshift = 0;
  }
  const int final_write = (C == 1) ? 1 : 0;
  const int iters = NN / (C * 64);     // 64-col tiles per chunk

  proj_kernel<<<NN / 8, 256, 0, stream>>>(h, Ws, Wt, Wc, whs_hi, whs_lo,
                                          wht_hi, wht_lo, whcT);
  attn_kernel<<<(NN / 64) * C, 256, 0, stream>>>(
      whs_hi, whs_lo, wht_hi, wht_lo, whcT, adj, Opart, mpart, lpart, out,
      iters, cshift, final_write);
  if (!final_write)
    combine_kernel<<<NN * OUTF / 256, 256, 0, stream>>>(Opart, mpart, lpart,
                                                        out, C);
}